// Round 2
// baseline (119.926 us; speedup 1.0000x reference)
//
#include <hip/hip_runtime.h>
#include <float.h>
#include <stdint.h>

// Problem: dist[b, tails[e]] += ew[e] where heads[e]==batch[b,0,0] && etype[e]==batch[b,0,2],
// then row-softmax(dist) over N=50000 nodes. B=64, E=1e6.
// Matches are rare (~0.084 expected per row) -> dist is ~all zeros.
// Structure (3 dispatches total):
//   1. memset cnt (256 B)
//   2. scatter: int4-vectorized edge scan (4 edges/thread) + LDS bloom filter,
//      compact matches into per-row (tail, weight) entry lists in ws.
//   3. fused fill: per-block analytic softmax params (thread 0 -> LDS), float4
//      constant fill with inline fixup of the <=few nonzero positions + ALPHA.

#define KCAP 1024   // max stored matches per row; real count is <= ~3
#define NDCAP 128   // dedup capacity in the fused fill (overkill-safe)

struct Entry { int t; float v; };

__global__ void scatter_kernel(const int* __restrict__ edge_index,  // (2,E) flat: heads then tails
                               const int* __restrict__ etype,       // (E,)
                               const float* __restrict__ ew,        // (E,)
                               const int* __restrict__ batch,       // (B,32,3) flat
                               int* __restrict__ cnt,               // (B,) pre-zeroed
                               Entry* __restrict__ entries,         // (B,KCAP)
                               int E, int B) {
    __shared__ unsigned s_keys[256];
    __shared__ unsigned s_bloom[64];   // 2048 bits
    for (int i = threadIdx.x; i < 64; i += blockDim.x) s_bloom[i] = 0u;
    __syncthreads();
    for (int i = threadIdx.x; i < B; i += blockDim.x) {
        unsigned h = (unsigned)batch[i * 96 + 0];   // batch[b,0,0]
        unsigned r = (unsigned)batch[i * 96 + 2];   // batch[b,0,2]
        unsigned key = (h << 16) | (r & 0xFFFFu);   // h<50000, r<237 — both fit 16 bits
        s_keys[i] = key;
        unsigned hs = (key * 2654435761u) >> 21;    // 11-bit hash
        atomicOr(&s_bloom[hs >> 5], 1u << (hs & 31u));
    }
    __syncthreads();

    const int e0 = (blockIdx.x * blockDim.x + threadIdx.x) * 4;
    if (e0 >= E) return;

    int4 hh, rr;
    if (e0 + 3 < E) {                     // aligned 16B loads (E%4==0 here, so always)
        hh = *(const int4*)(edge_index + e0);
        rr = *(const int4*)(etype + e0);
    } else {
        int* ph = (int*)&hh; int* pr = (int*)&rr;
        for (int u = 0; u < 4; ++u) {
            int e = e0 + u;
            ph[u] = (e < E) ? edge_index[e] : -1;
            pr[u] = (e < E) ? etype[e] : -1;
        }
    }

#pragma unroll
    for (int u = 0; u < 4; ++u) {
        int e = e0 + u;
        if (e >= E) break;
        unsigned h = ((const unsigned*)&hh)[u];
        unsigned r = ((const unsigned*)&rr)[u];
        unsigned key = (h << 16) | (r & 0xFFFFu);
        unsigned hs = (key * 2654435761u) >> 21;
        if (!(s_bloom[hs >> 5] & (1u << (hs & 31u)))) continue;   // bloom reject (~97%)

        int tail = -1;
        float w = 0.0f;
        for (int b = 0; b < B; ++b) {
            if (s_keys[b] == key) {
                if (tail < 0) { tail = edge_index[E + e]; w = ew[e]; }
                int idx = atomicAdd(&cnt[b], 1);
                if (idx < KCAP) {
                    entries[b * KCAP + idx].t = tail;
                    entries[b * KCAP + idx].v = w;
                }
            }
        }
    }
}

// One block-column per row b. Thread 0: dedup entries + closed-form softmax:
//   M = max(0, max v_j);  S = (N-nd)*exp(-M) + sum exp(v_j - M)
//   output = exp(-M)/S everywhere except positions t_j -> exp(v_j-M)/S.
// All blocks of a row read identical memory -> identical params (deterministic).
__global__ void fill4_fused_kernel(const int* __restrict__ cnt,
                                   const Entry* __restrict__ entries,
                                   float* __restrict__ out,
                                   int N4, int N, int B) {
    __shared__ int   s_td[NDCAP];
    __shared__ float s_vd[NDCAP];
    __shared__ int   s_nd;
    __shared__ float s_base;
    const int b = blockIdx.y;
    if (threadIdx.x == 0) {
        const Entry* row = entries + (size_t)b * KCAP;
        int k = min(cnt[b], KCAP);
        int nd = 0;
        for (int i = 0; i < k; ++i) {           // O(k^2), k is tiny
            int t = row[i].t; float v = row[i].v;
            int j = 0;
            for (; j < nd; ++j) if (s_td[j] == t) break;
            if (j < nd) s_vd[j] += v;
            else if (nd < NDCAP) { s_td[nd] = t; s_vd[nd] = v; ++nd; }
        }
        float M = 0.0f;                          // zeros dominate the row
        for (int j = 0; j < nd; ++j) M = fmaxf(M, s_vd[j]);
        float S = (float)(N - nd) * expf(-M);
        for (int j = 0; j < nd; ++j) { float e = expf(s_vd[j] - M); s_vd[j] = e; S += e; }
        float inv = 1.0f / S;
        for (int j = 0; j < nd; ++j) s_vd[j] *= inv;
        s_base = expf(-M) * inv;
        s_nd = nd;
    }
    __syncthreads();

    const int   nd   = s_nd;
    const float base = s_base;
    const int i4 = blockIdx.x * blockDim.x + threadIdx.x;
    if (i4 < N4) {
        float4 v = make_float4(base, base, base, base);
        const int eBase = i4 << 2;
        for (int j = 0; j < nd; ++j) {           // nd==0 for almost every block
            int d = s_td[j] - eBase;
            if ((unsigned)d < 4u) ((float*)&v)[d] = s_vd[j];
        }
        ((float4*)(out + (size_t)b * N))[i4] = v;
    }
    if (b == 0 && blockIdx.x == 0 && threadIdx.x == 0)
        out[(size_t)B * N] = 0.0f;               // ALPHA
}

// Generic scalar fallback (N % 4 != 0) — same fused logic.
__global__ void fill1_fused_kernel(const int* __restrict__ cnt,
                                   const Entry* __restrict__ entries,
                                   float* __restrict__ out,
                                   int N, int B) {
    __shared__ int   s_td[NDCAP];
    __shared__ float s_vd[NDCAP];
    __shared__ int   s_nd;
    __shared__ float s_base;
    const int b = blockIdx.y;
    if (threadIdx.x == 0) {
        const Entry* row = entries + (size_t)b * KCAP;
        int k = min(cnt[b], KCAP);
        int nd = 0;
        for (int i = 0; i < k; ++i) {
            int t = row[i].t; float v = row[i].v;
            int j = 0;
            for (; j < nd; ++j) if (s_td[j] == t) break;
            if (j < nd) s_vd[j] += v;
            else if (nd < NDCAP) { s_td[nd] = t; s_vd[nd] = v; ++nd; }
        }
        float M = 0.0f;
        for (int j = 0; j < nd; ++j) M = fmaxf(M, s_vd[j]);
        float S = (float)(N - nd) * expf(-M);
        for (int j = 0; j < nd; ++j) { float e = expf(s_vd[j] - M); s_vd[j] = e; S += e; }
        float inv = 1.0f / S;
        for (int j = 0; j < nd; ++j) s_vd[j] *= inv;
        s_base = expf(-M) * inv;
        s_nd = nd;
    }
    __syncthreads();

    const int   nd   = s_nd;
    const float base = s_base;
    const int i = blockIdx.x * blockDim.x + threadIdx.x;
    if (i < N) {
        float v = base;
        for (int j = 0; j < nd; ++j) if (s_td[j] == i) v = s_vd[j];
        out[(size_t)b * N + i] = v;
    }
    if (b == 0 && blockIdx.x == 0 && threadIdx.x == 0)
        out[(size_t)B * N] = 0.0f;               // ALPHA
}

extern "C" void kernel_launch(void* const* d_in, const int* in_sizes, int n_in,
                              void* d_out, int out_size, void* d_ws, size_t ws_size,
                              hipStream_t stream) {
    const int*   edge_index = (const int*)d_in[0];   // (2,E)
    const int*   edge_type  = (const int*)d_in[1];   // (E,)
    const int*   batch      = (const int*)d_in[2];   // (B,32,3)
    const float* ew         = (const float*)d_in[3]; // (E,)
    // d_in[4] = num_nodes (device scalar) — derived from host-known sizes instead.

    const int E = in_sizes[1];
    const int B = in_sizes[2] / 96;          // 32*3 per batch row
    const int N = (out_size - 1) / B;        // out = (B,N) softmax + 1 ALPHA scalar

    float* out = (float*)d_out;

    // workspace layout
    char*  ws      = (char*)d_ws;
    int*   cnt     = (int*)ws;               // B ints
    Entry* entries = (Entry*)(ws + 4096);    // B*KCAP entries (~512 KB)

    hipMemsetAsync(cnt, 0, B * sizeof(int), stream);   // tiny — only the counters

    const int threads = 256;
    const int edgesPerBlock = threads * 4;
    scatter_kernel<<<(E + edgesPerBlock - 1) / edgesPerBlock, threads, 0, stream>>>(
        edge_index, edge_type, ew, batch, cnt, entries, E, B);

    if ((N & 3) == 0) {
        const int N4 = N >> 2;
        fill4_fused_kernel<<<dim3((N4 + 255) / 256, B), 256, 0, stream>>>(
            cnt, entries, out, N4, N, B);
    } else {
        fill1_fused_kernel<<<dim3((N + 255) / 256, B), 256, 0, stream>>>(
            cnt, entries, out, N, B);
    }
}

// Round 3
// 98.246 us; speedup vs baseline: 1.2207x; 1.2207x over previous
//
#include <hip/hip_runtime.h>
#include <float.h>
#include <stdint.h>

// Problem: dist[b, tails[e]] += ew[e] where heads[e]==batch[b,0,0] && etype[e]==batch[b,0,2],
// then row-softmax(dist) over N=50000 nodes. B=64, E=1e6.
// Matches are rare (~0.084 expected per row) -> dist is ~all zeros.
// Structure (round-1 proven 94us baseline, ONLY change: int4-vectorized scatter):
//   1. memset cnt (256 B)
//   2. scatter: int4 edge scan (4 edges/thread) + LDS bloom, compact matches into ws
//   3. rowparams: 1 block, closed-form softmax params per row
//   4. fill: float4 constant fill (rowBase[b] uniform broadcast load, no serial section)
//   5. fixup: overwrite the <=few nonzero positions + ALPHA

#define KCAP 1024   // max stored matches per row; real count is <= ~3

struct Entry { int t; float v; };

__global__ void scatter_kernel(const int* __restrict__ edge_index,  // (2,E) flat: heads then tails
                               const int* __restrict__ etype,       // (E,)
                               const float* __restrict__ ew,        // (E,)
                               const int* __restrict__ batch,       // (B,32,3) flat
                               int* __restrict__ cnt,               // (B,) pre-zeroed
                               Entry* __restrict__ entries,         // (B,KCAP)
                               int E, int B) {
    __shared__ unsigned s_keys[256];
    __shared__ unsigned s_bloom[64];   // 2048 bits
    for (int i = threadIdx.x; i < 64; i += blockDim.x) s_bloom[i] = 0u;
    __syncthreads();
    for (int i = threadIdx.x; i < B; i += blockDim.x) {
        unsigned h = (unsigned)batch[i * 96 + 0];   // batch[b,0,0]
        unsigned r = (unsigned)batch[i * 96 + 2];   // batch[b,0,2]
        unsigned key = (h << 16) | (r & 0xFFFFu);   // h<50000, r<237 — both fit 16 bits
        s_keys[i] = key;
        unsigned hs = (key * 2654435761u) >> 21;    // 11-bit hash
        atomicOr(&s_bloom[hs >> 5], 1u << (hs & 31u));
    }
    __syncthreads();

    const int e0 = (blockIdx.x * blockDim.x + threadIdx.x) * 4;
    if (e0 >= E) return;

    int4 hh, rr;
    if (e0 + 3 < E) {                     // aligned 16B loads (E%4==0 here, so always)
        hh = *(const int4*)(edge_index + e0);
        rr = *(const int4*)(etype + e0);
    } else {
        int* ph = (int*)&hh; int* pr = (int*)&rr;
        for (int u = 0; u < 4; ++u) {
            int e = e0 + u;
            ph[u] = (e < E) ? edge_index[e] : -1;
            pr[u] = (e < E) ? etype[e] : -1;
        }
    }

#pragma unroll
    for (int u = 0; u < 4; ++u) {
        int e = e0 + u;
        if (e >= E) break;
        unsigned h = ((const unsigned*)&hh)[u];
        unsigned r = ((const unsigned*)&rr)[u];
        unsigned key = (h << 16) | (r & 0xFFFFu);
        unsigned hs = (key * 2654435761u) >> 21;
        if (!(s_bloom[hs >> 5] & (1u << (hs & 31u)))) continue;   // bloom reject (~97%)

        int tail = -1;
        float w = 0.0f;
        for (int b = 0; b < B; ++b) {
            if (s_keys[b] == key) {
                if (tail < 0) { tail = edge_index[E + e]; w = ew[e]; }
                int idx = atomicAdd(&cnt[b], 1);
                if (idx < KCAP) {
                    entries[b * KCAP + idx].t = tail;
                    entries[b * KCAP + idx].v = w;
                }
            }
        }
    }
}

// One thread per row: aggregate duplicate tails, then closed-form softmax params.
// Row has nd distinct nonzeros v_j and (N-nd) zeros:
//   M = max(0, max v_j);  S = (N-nd)*exp(-M) + sum exp(v_j - M)
//   output = exp(-M)/S everywhere except positions t_j, which get exp(v_j-M)/S.
__global__ void rowparams_kernel(const int* __restrict__ cnt,
                                 Entry* __restrict__ entries,
                                 float* __restrict__ rowBase,
                                 int* __restrict__ dcnt,
                                 int N, int B) {
    int b = threadIdx.x + blockIdx.x * blockDim.x;
    if (b >= B) return;
    Entry* row = entries + (size_t)b * KCAP;
    int k = min(cnt[b], KCAP);

    // dedup/aggregate in place (k is tiny; O(k^2) is fine)
    int nd = 0;
    for (int i = 0; i < k; ++i) {
        int t = row[i].t;
        float v = row[i].v;
        int j = 0;
        for (; j < nd; ++j) if (row[j].t == t) break;
        if (j < nd) row[j].v += v;
        else { row[nd].t = t; row[nd].v = v; ++nd; }
    }

    float M = 0.0f;                              // zeros exist since nd <= KCAP << N
    for (int j = 0; j < nd; ++j) M = fmaxf(M, row[j].v);
    float S = (float)(N - nd) * expf(-M);
    for (int j = 0; j < nd; ++j) {
        float e = expf(row[j].v - M);
        S += e;
        row[j].v = e;                            // stash numerator
    }
    for (int j = 0; j < nd; ++j) row[j].v = row[j].v / S;
    rowBase[b] = expf(-M) / S;
    dcnt[b] = nd;
}

// Full-grid constant fill: row b <- rowBase[b]. float4 path (N%4==0 for this problem).
__global__ void fill4_kernel(float* __restrict__ out, const float* __restrict__ rowBase, int N4, int N) {
    int i4 = blockIdx.x * blockDim.x + threadIdx.x;
    float base = rowBase[blockIdx.y];            // uniform -> broadcast load, L2 hit
    if (i4 < N4) {
        float4* row4 = (float4*)(out + (size_t)blockIdx.y * N);
        row4[i4] = make_float4(base, base, base, base);
    }
}
__global__ void fill1_kernel(float* __restrict__ out, const float* __restrict__ rowBase, int N) {
    int i = blockIdx.x * blockDim.x + threadIdx.x;
    float base = rowBase[blockIdx.y];
    if (i < N) out[(size_t)blockIdx.y * N + i] = base;
}

// Overwrite the few nonzero positions; write ALPHA (=0) scalar at out[B*N].
__global__ void fixup_kernel(const int* __restrict__ dcnt,
                             const Entry* __restrict__ entries,
                             float* __restrict__ out, int N, int B) {
    int b = threadIdx.x;
    if (b < B) {
        int nd = dcnt[b];
        const Entry* row = entries + (size_t)b * KCAP;
        for (int j = 0; j < nd; ++j) out[(size_t)b * N + row[j].t] = row[j].v;
    }
    if (threadIdx.x == 0) out[(size_t)B * N] = 0.0f;   // ALPHA
}

extern "C" void kernel_launch(void* const* d_in, const int* in_sizes, int n_in,
                              void* d_out, int out_size, void* d_ws, size_t ws_size,
                              hipStream_t stream) {
    const int*   edge_index = (const int*)d_in[0];   // (2,E)
    const int*   edge_type  = (const int*)d_in[1];   // (E,)
    const int*   batch      = (const int*)d_in[2];   // (B,32,3)
    const float* ew         = (const float*)d_in[3]; // (E,)
    // d_in[4] = num_nodes (device scalar) — derived from host-known sizes instead.

    const int E = in_sizes[1];
    const int B = in_sizes[2] / 96;          // 32*3 per batch row
    const int N = (out_size - 1) / B;        // out = (B,N) softmax + 1 ALPHA scalar

    float* out = (float*)d_out;

    // workspace layout
    char*  ws      = (char*)d_ws;
    int*   cnt     = (int*)ws;               // B ints
    float* rowBase = (float*)(ws + 1024);    // B floats
    int*   dcnt    = (int*)(ws + 2048);      // B ints
    Entry* entries = (Entry*)(ws + 4096);    // B*KCAP entries (~512 KB)

    hipMemsetAsync(cnt, 0, B * sizeof(int), stream);   // tiny — only the counters

    const int threads = 256;
    const int edgesPerBlock = threads * 4;
    scatter_kernel<<<(E + edgesPerBlock - 1) / edgesPerBlock, threads, 0, stream>>>(
        edge_index, edge_type, ew, batch, cnt, entries, E, B);

    const int rpThreads = ((B + 63) / 64) * 64;
    rowparams_kernel<<<1, rpThreads, 0, stream>>>(cnt, entries, rowBase, dcnt, N, B);

    if ((N & 3) == 0) {
        const int N4 = N >> 2;
        fill4_kernel<<<dim3((N4 + 255) / 256, B), 256, 0, stream>>>(out, rowBase, N4, N);
    } else {
        fill1_kernel<<<dim3((N + 255) / 256, B), 256, 0, stream>>>(out, rowBase, N);
    }

    fixup_kernel<<<1, 256, 0, stream>>>(dcnt, entries, out, N, B);
}

// Round 4
// 90.736 us; speedup vs baseline: 1.3217x; 1.0828x over previous
//
#include <hip/hip_runtime.h>
#include <float.h>
#include <stdint.h>

// Problem: dist[b, tails[e]] += ew[e] where heads[e]==batch[b,0,0] && etype[e]==batch[b,0,2],
// then row-softmax(dist) over N=50000 nodes. B=64, E=1e6.
// Matches are rare (~0.084 expected per row) -> dist is ~all zeros.
// So: compact sparse scatter + ANALYTIC softmax (constant base value per row + tiny fixup).
// This is the round-1 structure (best measured: 94.0 us), reverted exactly:
//   1. memset cnt (256 B)
//   2. scatter: scalar edge scan + LDS bloom filter, compact matches into ws
//   3. rowparams: 1 block, closed-form softmax params per row
//   4. fill: float4 constant fill (rowBase[b] uniform broadcast load)
//   5. fixup: overwrite the <=few nonzero positions + ALPHA
// Round-2 lesson: folding rowparams/fixup into the fill (per-block param
// recompute + LDS broadcast in all 3136 blocks) cost ~22 us — do not re-fuse.
// Round-3 lesson: int4-vectorizing the scatter was neutral-to-negative (98.2).

#define KCAP 1024   // max stored matches per row; real count is <= ~3

struct Entry { int t; float v; };

// One thread per edge. Batch keys staged in LDS + 2048-bit bloom filter so
// ~97% of edges skip the B-way compare loop entirely.
__global__ void scatter_kernel(const int* __restrict__ edge_index,  // (2,E) flat: heads then tails
                               const int* __restrict__ etype,       // (E,)
                               const float* __restrict__ ew,        // (E,)
                               const int* __restrict__ batch,       // (B,32,3) flat
                               int* __restrict__ cnt,               // (B,) pre-zeroed
                               Entry* __restrict__ entries,         // (B,KCAP)
                               int E, int B) {
    __shared__ unsigned s_keys[256];
    __shared__ unsigned s_bloom[64];   // 2048 bits
    for (int i = threadIdx.x; i < 64; i += blockDim.x) s_bloom[i] = 0u;
    __syncthreads();
    for (int i = threadIdx.x; i < B; i += blockDim.x) {
        unsigned h = (unsigned)batch[i * 96 + 0];   // batch[b,0,0]
        unsigned r = (unsigned)batch[i * 96 + 2];   // batch[b,0,2]
        unsigned key = (h << 16) | (r & 0xFFFFu);   // h<50000, r<237 — both fit 16 bits
        s_keys[i] = key;
        unsigned hs = (key * 2654435761u) >> 21;    // 11-bit hash
        atomicOr(&s_bloom[hs >> 5], 1u << (hs & 31u));
    }
    __syncthreads();

    int e = blockIdx.x * blockDim.x + threadIdx.x;
    if (e >= E) return;
    unsigned key = ((unsigned)edge_index[e] << 16) | ((unsigned)etype[e] & 0xFFFFu);
    unsigned hs = (key * 2654435761u) >> 21;
    if (!(s_bloom[hs >> 5] & (1u << (hs & 31u)))) return;   // bloom reject (~97%)

    int tail = -1;
    float w = 0.0f;
    for (int b = 0; b < B; ++b) {
        if (s_keys[b] == key) {
            if (tail < 0) { tail = edge_index[E + e]; w = ew[e]; }
            int idx = atomicAdd(&cnt[b], 1);
            if (idx < KCAP) { entries[b * KCAP + idx].t = tail; entries[b * KCAP + idx].v = w; }
        }
    }
}

// One thread per row: aggregate duplicate tails, then closed-form softmax params.
// Row has nd distinct nonzeros v_j and (N-nd) zeros:
//   M = max(0, max v_j);  S = (N-nd)*exp(-M) + sum exp(v_j - M)
//   output = exp(-M)/S everywhere except positions t_j, which get exp(v_j-M)/S.
__global__ void rowparams_kernel(const int* __restrict__ cnt,
                                 Entry* __restrict__ entries,
                                 float* __restrict__ rowBase,
                                 int* __restrict__ dcnt,
                                 int N, int B) {
    int b = threadIdx.x + blockIdx.x * blockDim.x;
    if (b >= B) return;
    Entry* row = entries + (size_t)b * KCAP;
    int k = min(cnt[b], KCAP);

    // dedup/aggregate in place (k is tiny; O(k^2) is fine)
    int nd = 0;
    for (int i = 0; i < k; ++i) {
        int t = row[i].t;
        float v = row[i].v;
        int j = 0;
        for (; j < nd; ++j) if (row[j].t == t) break;
        if (j < nd) row[j].v += v;
        else { row[nd].t = t; row[nd].v = v; ++nd; }
    }

    float M = 0.0f;                              // zeros exist since nd <= KCAP << N
    for (int j = 0; j < nd; ++j) M = fmaxf(M, row[j].v);
    float S = (float)(N - nd) * expf(-M);
    for (int j = 0; j < nd; ++j) {
        float e = expf(row[j].v - M);
        S += e;
        row[j].v = e;                            // stash numerator
    }
    for (int j = 0; j < nd; ++j) row[j].v = row[j].v / S;
    rowBase[b] = expf(-M) / S;
    dcnt[b] = nd;
}

// Full-grid constant fill: row b <- rowBase[b]. float4 path (N%4==0 for this problem).
__global__ void fill4_kernel(float* __restrict__ out, const float* __restrict__ rowBase, int N4, int N) {
    int i4 = blockIdx.x * blockDim.x + threadIdx.x;
    float base = rowBase[blockIdx.y];            // uniform -> broadcast load, L2 hit
    if (i4 < N4) {
        float4* row4 = (float4*)(out + (size_t)blockIdx.y * N);
        row4[i4] = make_float4(base, base, base, base);
    }
}
__global__ void fill1_kernel(float* __restrict__ out, const float* __restrict__ rowBase, int N) {
    int i = blockIdx.x * blockDim.x + threadIdx.x;
    float base = rowBase[blockIdx.y];
    if (i < N) out[(size_t)blockIdx.y * N + i] = base;
}

// Overwrite the few nonzero positions; write ALPHA (=0) scalar at out[B*N].
__global__ void fixup_kernel(const int* __restrict__ dcnt,
                             const Entry* __restrict__ entries,
                             float* __restrict__ out, int N, int B) {
    int b = threadIdx.x;
    if (b < B) {
        int nd = dcnt[b];
        const Entry* row = entries + (size_t)b * KCAP;
        for (int j = 0; j < nd; ++j) out[(size_t)b * N + row[j].t] = row[j].v;
    }
    if (threadIdx.x == 0) out[(size_t)B * N] = 0.0f;   // ALPHA
}

extern "C" void kernel_launch(void* const* d_in, const int* in_sizes, int n_in,
                              void* d_out, int out_size, void* d_ws, size_t ws_size,
                              hipStream_t stream) {
    const int*   edge_index = (const int*)d_in[0];   // (2,E)
    const int*   edge_type  = (const int*)d_in[1];   // (E,)
    const int*   batch      = (const int*)d_in[2];   // (B,32,3)
    const float* ew         = (const float*)d_in[3]; // (E,)
    // d_in[4] = num_nodes (device scalar) — derived from host-known sizes instead.

    const int E = in_sizes[1];
    const int B = in_sizes[2] / 96;          // 32*3 per batch row
    const int N = (out_size - 1) / B;        // out = (B,N) softmax + 1 ALPHA scalar

    float* out = (float*)d_out;

    // workspace layout
    char*  ws      = (char*)d_ws;
    int*   cnt     = (int*)ws;               // B ints
    float* rowBase = (float*)(ws + 1024);    // B floats
    int*   dcnt    = (int*)(ws + 2048);      // B ints
    Entry* entries = (Entry*)(ws + 4096);    // B*KCAP entries (~512 KB)

    hipMemsetAsync(cnt, 0, B * sizeof(int), stream);   // tiny — only the counters

    const int threads = 256;
    scatter_kernel<<<(E + threads - 1) / threads, threads, 0, stream>>>(
        edge_index, edge_type, ew, batch, cnt, entries, E, B);

    const int rpThreads = ((B + 63) / 64) * 64;
    rowparams_kernel<<<1, rpThreads, 0, stream>>>(cnt, entries, rowBase, dcnt, N, B);

    if ((N & 3) == 0) {
        const int N4 = N >> 2;
        fill4_kernel<<<dim3((N4 + 255) / 256, B), 256, 0, stream>>>(out, rowBase, N4, N);
    } else {
        fill1_kernel<<<dim3((N + 255) / 256, B), 256, 0, stream>>>(out, rowBase, N);
    }

    fixup_kernel<<<1, 256, 0, stream>>>(dcnt, entries, out, N, B);
}